// Round 1
// baseline (135.260 us; speedup 1.0000x reference)
//
#include <hip/hip_runtime.h>

// KAN B-spline activation, cubic (order 3), G=5 knots per feature.
// Strategy: one thread per feature column, loop over rows.
//  - All per-feature constants (extended knots, folded reciprocals, coeffs)
//    live in registers, amortized over ROWS_PER_BLOCK rows.
//  - Cox-de Boor with u = fmaf(x, r, s) and right-coeff = (1 - u[i+1])
//    => 2 FMA per recurrence output, 1 FMA per u.
//  - Degree-0 via monotone step difference (no boolean and/select chains).

constexpr int FEAT  = 768;
constexpr int GSZ   = 5;               // grid size (knots per feature)
constexpr int ORD   = 3;               // spline order
constexpr int KE    = GSZ + 2 * ORD;   // 11 extended knots
constexpr int NB0   = KE - 1;          // 10 degree-0 indicators
constexpr int NCOEF = GSZ + ORD - 1;   // 7 coefficients
constexpr float EPSV = 1e-8f;
constexpr int ROWS_PER_BLOCK = 32;

__global__ __launch_bounds__(256)
void kan_bspline_kernel(const float* __restrict__ xg,
                        const float* __restrict__ knots,
                        const float* __restrict__ coeffs,
                        const float* __restrict__ scaler,
                        float* __restrict__ outg,
                        int nrows)
{
    const int f    = blockIdx.x * blockDim.x + threadIdx.x;  // feature column, 0..767
    const int row0 = blockIdx.y * ROWS_PER_BLOCK;
    if (row0 >= nrows) return;

    // ---- per-feature constants (registers, reused across all rows) ----
    float kn[GSZ];
#pragma unroll
    for (int i = 0; i < GSZ; ++i) kn[i] = knots[f * GSZ + i];
    const float h = (kn[GSZ - 1] - kn[0]) * (1.0f / (GSZ - 1));

    float te[KE];
#pragma unroll
    for (int i = 0; i < ORD; ++i) te[i] = kn[0] - h * (float)(ORD - i);
#pragma unroll
    for (int i = 0; i < GSZ; ++i) te[ORD + i] = kn[i];
#pragma unroll
    for (int i = 0; i < ORD; ++i) te[ORD + GSZ + i] = kn[GSZ - 1] + h * (float)(i + 1);

    // u_d[j] = (x - te[j]) / (te[j+d] - te[j] + EPS) == fmaf(x, r_d[j], s_d[j])
    float r1[KE - 1], s1[KE - 1];
#pragma unroll
    for (int j = 0; j < KE - 1; ++j) {
        r1[j] = 1.0f / (te[j + 1] - te[j] + EPSV);
        s1[j] = -te[j] * r1[j];
    }
    float r2[KE - 2], s2[KE - 2];
#pragma unroll
    for (int j = 0; j < KE - 2; ++j) {
        r2[j] = 1.0f / (te[j + 2] - te[j] + EPSV);
        s2[j] = -te[j] * r2[j];
    }
    float r3[KE - 3], s3[KE - 3];
#pragma unroll
    for (int j = 0; j < KE - 3; ++j) {
        r3[j] = 1.0f / (te[j + 3] - te[j] + EPSV);
        s3[j] = -te[j] * r3[j];
    }

    float cf[NCOEF];
#pragma unroll
    for (int j = 0; j < NCOEF; ++j) cf[j] = coeffs[f * NCOEF + j];
    const float sc = scaler[f];

    const float* xp = xg   + (size_t)row0 * FEAT + f;
    float*       op = outg + (size_t)row0 * FEAT + f;
    const int rows = (nrows - row0 < ROWS_PER_BLOCK) ? (nrows - row0) : ROWS_PER_BLOCK;

    for (int rr = 0; rr < rows; ++rr) {
        const float x = xp[(size_t)rr * FEAT];

        // degree 0: b0[i] = [te[i] <= x < te[i+1]] = step(te[i]) - step(te[i+1])
        // (te strictly increasing => step sequence monotone non-increasing)
        float gef[KE];
#pragma unroll
        for (int i = 0; i < KE; ++i) gef[i] = (x >= te[i]) ? 1.0f : 0.0f;
        float b0[NB0];
#pragma unroll
        for (int i = 0; i < NB0; ++i) b0[i] = gef[i] - gef[i + 1];

        float u[KE - 1];

        // degree 1: b1[i] = u[i]*b0[i] + (1 - u[i+1])*b0[i+1]
#pragma unroll
        for (int j = 0; j < KE - 1; ++j) u[j] = fmaf(x, r1[j], s1[j]);
        float b1[KE - 2];
#pragma unroll
        for (int i = 0; i < KE - 2; ++i) {
            float t = fmaf(-u[i + 1], b0[i + 1], b0[i + 1]);
            b1[i] = fmaf(u[i], b0[i], t);
        }

        // degree 2
#pragma unroll
        for (int j = 0; j < KE - 2; ++j) u[j] = fmaf(x, r2[j], s2[j]);
        float b2[KE - 3];
#pragma unroll
        for (int i = 0; i < KE - 3; ++i) {
            float t = fmaf(-u[i + 1], b1[i + 1], b1[i + 1]);
            b2[i] = fmaf(u[i], b1[i], t);
        }

        // degree 3
#pragma unroll
        for (int j = 0; j < KE - 3; ++j) u[j] = fmaf(x, r3[j], s3[j]);
        float b3[KE - 4];
#pragma unroll
        for (int i = 0; i < KE - 4; ++i) {
            float t = fmaf(-u[i + 1], b2[i + 1], b2[i + 1]);
            b3[i] = fmaf(u[i], b2[i], t);
        }

        // dot with coeffs, scale
        float acc = 0.0f;
#pragma unroll
        for (int j = 0; j < NCOEF; ++j) acc = fmaf(b3[j], cf[j], acc);
        op[(size_t)rr * FEAT] = acc * sc;
    }
}

extern "C" void kernel_launch(void* const* d_in, const int* in_sizes, int n_in,
                              void* d_out, int out_size, void* d_ws, size_t ws_size,
                              hipStream_t stream) {
    const float* x      = (const float*)d_in[0];
    const float* knots  = (const float*)d_in[1];
    const float* coeffs = (const float*)d_in[2];
    const float* scaler = (const float*)d_in[3];
    float* out = (float*)d_out;

    const int nrows = in_sizes[0] / FEAT;  // B*S = 16384

    dim3 block(256, 1, 1);
    dim3 grid(FEAT / 256, (nrows + ROWS_PER_BLOCK - 1) / ROWS_PER_BLOCK, 1);
    kan_bspline_kernel<<<grid, block, 0, stream>>>(x, knots, coeffs, scaler, out, nrows);
}